// Round 2
// baseline (3814.034 us; speedup 1.0000x reference)
//
#include <hip/hip_runtime.h>
#include <math.h>

// Problem constants (B=4, S=512, H=2048, E=16, K=4)
#define M_TOK 2048   // B*S tokens
#define H_    2048
#define H2_   1024
#define E_    16
#define CAP_  768
#define ALPHA_ 0.7f

// ---------------------------------------------------------------------------
// Batched fp32 GEMM: C[M,N] = act(A[M,K] @ W[K,N] + bias[N])
// 128x128 tile, BK=16, 256 threads, 8x8 microtile, register prefetch.
// grid = (ntiles_max, M/128, ngemms); per-z descriptor.
// ---------------------------------------------------------------------------
struct GDesc {
    const float* A; const float* W; const float* bias; float* C;
    int K; int N; int ntiles; int relu;
};
struct GPack { GDesc g[4]; };

__global__ __launch_bounds__(256, 3) void gemm128_kernel(GPack pack)
{
    const GDesc d = pack.g[blockIdx.z];
    if ((int)blockIdx.x >= d.ntiles) return;

    // pad to 132 floats: 132%32=4 -> all store/read patterns <=2-way (free);
    // 132*4B=528B is 16B-multiple so float4 stays aligned.
    __shared__ float As[16][132];   // [k][m], transposed at store
    __shared__ float Bs[16][132];   // [k][n]

    const int tid = threadIdx.x;
    const int bm = blockIdx.y * 128;
    const int bn = blockIdx.x * 128;
    const int K = d.K, N = d.N;

    // A tile load: 128 rows x 16 k; thread -> (row=tid>>2, k4=(tid&3)*4), rows +0/+64
    const int ar  = tid >> 2;
    const int ak  = (tid & 3) << 2;
    // B tile load: 16 k x 128 n; thread -> (k=tid>>5, n4=(tid&31)*4), k +0/+8
    const int bk  = tid >> 5;
    const int bn4 = (tid & 31) << 2;

    const float* Aptr = d.A + (size_t)(bm + ar) * K + ak;
    const float* Wptr = d.W + (size_t)bk * N + bn + bn4;

    float4 a0 = *(const float4*)(Aptr);
    float4 a1 = *(const float4*)(Aptr + (size_t)64 * K);
    float4 b0 = *(const float4*)(Wptr);
    float4 b1 = *(const float4*)(Wptr + (size_t)8 * N);

    float acc[8][8];
#pragma unroll
    for (int i = 0; i < 8; ++i)
#pragma unroll
        for (int j = 0; j < 8; ++j) acc[i][j] = 0.f;

    const int tx = tid & 15;   // n group
    const int ty = tid >> 4;   // m group

    int k0 = 0;
    for (;;) {
        // staged regs -> LDS
        As[ak + 0][ar] = a0.x; As[ak + 1][ar] = a0.y;
        As[ak + 2][ar] = a0.z; As[ak + 3][ar] = a0.w;
        As[ak + 0][ar + 64] = a1.x; As[ak + 1][ar + 64] = a1.y;
        As[ak + 2][ar + 64] = a1.z; As[ak + 3][ar + 64] = a1.w;
        *(float4*)&Bs[bk][bn4]     = b0;
        *(float4*)&Bs[bk + 8][bn4] = b1;
        __syncthreads();

        k0 += 16;
        const bool more = (k0 < K);
        if (more) {   // prefetch next tile while computing this one
            a0 = *(const float4*)(Aptr + k0);
            a1 = *(const float4*)(Aptr + k0 + (size_t)64 * K);
            b0 = *(const float4*)(Wptr + (size_t)k0 * N);
            b1 = *(const float4*)(Wptr + (size_t)(k0 + 8) * N);
        }

#pragma unroll
        for (int k = 0; k < 16; ++k) {
            float4 x0 = *(const float4*)&As[k][(ty << 3)];
            float4 x1 = *(const float4*)&As[k][(ty << 3) + 4];
            float4 y0 = *(const float4*)&Bs[k][(tx << 3)];
            float4 y1 = *(const float4*)&Bs[k][(tx << 3) + 4];
            float a[8] = {x0.x, x0.y, x0.z, x0.w, x1.x, x1.y, x1.z, x1.w};
            float b[8] = {y0.x, y0.y, y0.z, y0.w, y1.x, y1.y, y1.z, y1.w};
#pragma unroll
            for (int i = 0; i < 8; ++i)
#pragma unroll
                for (int j = 0; j < 8; ++j)
                    acc[i][j] = fmaf(a[i], b[j], acc[i][j]);
        }
        if (!more) break;
        __syncthreads();
    }

    // epilogue: bias + optional relu, 8 rows x 2 float4 per thread
    const float4 bb0 = *(const float4*)&d.bias[bn + (tx << 3)];
    const float4 bb1 = *(const float4*)&d.bias[bn + (tx << 3) + 4];
    const float bv[8] = {bb0.x, bb0.y, bb0.z, bb0.w, bb1.x, bb1.y, bb1.z, bb1.w};
#pragma unroll
    for (int i = 0; i < 8; ++i) {
        const size_t row = (size_t)(bm + (ty << 3) + i);
        float o[8];
#pragma unroll
        for (int j = 0; j < 8; ++j) {
            o[j] = acc[i][j] + bv[j];
            if (d.relu) o[j] = fmaxf(o[j], 0.f);
        }
        float4 o0 = {o[0], o[1], o[2], o[3]};
        float4 o1 = {o[4], o[5], o[6], o[7]};
        *(float4*)&d.C[row * N + bn + (tx << 3)]     = o0;
        *(float4*)&d.C[row * N + bn + (tx << 3) + 4] = o1;
    }
}

// ---------------------------------------------------------------------------
// Batched skinny GEMM: C[M,16] = A[M,K] @ W[K,16] + bias[16]
// block = 16 rows x 16 experts; W chunk staged in LDS; grid (M/16, 1, ngemms).
// ---------------------------------------------------------------------------
struct SDesc { const float* A; const float* W; const float* bias; float* C; int K; };
struct SPack { SDesc g[5]; };

__global__ __launch_bounds__(256) void gemm_n16_kernel(SPack pack)
{
    const SDesc d = pack.g[blockIdx.z];
    __shared__ float As[16][68];   // pad 68: reads 2-way max; 272B keeps f4 align
    __shared__ float Ws[64][16];

    const int tid = threadIdx.x;
    const int e = tid & 15;
    const int r = tid >> 4;
    const int row0 = blockIdx.x * 16;

    const int lr  = tid >> 4;            // A load: row 0..15
    const int lk4 = (tid & 15) << 2;     // A load: k offset
    const int wk  = tid >> 2;            // W load: k row 0..63
    const int we4 = (tid & 3) << 2;      // W load: expert offset

    const int K = d.K;
    float acc = 0.f;
    for (int k0 = 0; k0 < K; k0 += 64) {
        *(float4*)&As[lr][lk4] =
            *(const float4*)&d.A[(size_t)(row0 + lr) * K + k0 + lk4];
        *(float4*)&Ws[wk][we4] =
            *(const float4*)&d.W[(size_t)(k0 + wk) * E_ + we4];
        __syncthreads();
#pragma unroll
        for (int kk = 0; kk < 64; kk += 4) {
            float4 a = *(const float4*)&As[r][kk];
            acc = fmaf(a.x, Ws[kk + 0][e], acc);
            acc = fmaf(a.y, Ws[kk + 1][e], acc);
            acc = fmaf(a.z, Ws[kk + 2][e], acc);
            acc = fmaf(a.w, Ws[kk + 3][e], acc);
        }
        __syncthreads();
    }
    d.C[(size_t)(row0 + r) * E_ + e] = acc + d.bias[e];
}

// ---------------------------------------------------------------------------
// Router finalize
// ---------------------------------------------------------------------------
__device__ __forceinline__ void softmax16_acc(const float* __restrict__ lg,
                                              float w, float* __restrict__ p)
{
    float mx = lg[0];
#pragma unroll
    for (int e = 1; e < 16; ++e) mx = fmaxf(mx, lg[e]);
    float ex[16];
    float s = 0.f;
#pragma unroll
    for (int e = 0; e < 16; ++e) { ex[e] = expf(lg[e] - mx); s += ex[e]; }
    const float wi = w / s;
#pragma unroll
    for (int e = 0; e < 16; ++e) p[e] = fmaf(ex[e], wi, p[e]);
}

__global__ __launch_bounds__(256) void router_kernel(
    const float* __restrict__ GL,   // [M,16]
    const float* __restrict__ SL,   // [4,M,16]
    float* __restrict__ out, float* __restrict__ accum)
{
    const int t = blockIdx.x * 256 + threadIdx.x;

    float p[16];
#pragma unroll
    for (int e = 0; e < 16; ++e) p[e] = 0.f;

    softmax16_acc(GL + (size_t)t * E_, ALPHA_, p);
#pragma unroll
    for (int m = 0; m < 4; ++m)
        softmax16_acc(SL + ((size_t)m * M_TOK + t) * E_, (1.f - ALPHA_) * 0.5f, p);

    const size_t NTOT = (size_t)M_TOK * E_ * CAP_;
    float* probs_out = out + 2 * NTOT + (size_t)t * E_;
#pragma unroll
    for (int e = 0; e < 16; ++e) probs_out[e] = p[e];

    // wave butterfly reduction for aux-loss accumulator (1 atomic per expert
    // per wave instead of per thread: kills same-address atomic serialization)
    float red[16];
#pragma unroll
    for (int e = 0; e < 16; ++e) red[e] = p[e];
#pragma unroll
    for (int m = 1; m < 64; m <<= 1)
#pragma unroll
        for (int e = 0; e < 16; ++e) red[e] += __shfl_xor(red[e], m);
    const int lane = threadIdx.x & 63;
#pragma unroll
    for (int e = 0; e < 16; ++e)
        if (lane == e) atomicAdd(&accum[e], red[e]);

    // top-4, ties -> lowest index (matches jax.lax.top_k)
    float tmp[16];
#pragma unroll
    for (int e = 0; e < 16; ++e) tmp[e] = p[e];
    int   bi[4];
    float bv[4];
    float s4 = 0.f;
#pragma unroll
    for (int kk = 0; kk < 4; ++kk) {
        float best = -1.f; int besti = 0;
#pragma unroll
        for (int e = 0; e < 16; ++e)
            if (tmp[e] > best) { best = tmp[e]; besti = e; }
        bi[kk] = besti; bv[kk] = best; s4 += best;
        tmp[besti] = -1.f;
    }
    const float inv = 1.f / s4;
#pragma unroll
    for (int kk = 0; kk < 4; ++kk) {
        const size_t base = ((size_t)t * E_ + bi[kk]) * CAP_;
        out[base] = 1.0f;                    // dispatch_tensor slot 0
        out[NTOT + base] = bv[kk] * inv;     // combine_tensor  slot 0
    }
}

__global__ void aux_kernel(const float* __restrict__ accum,
                           float* __restrict__ out, unsigned long long pos)
{
    if (threadIdx.x == 0 && blockIdx.x == 0) {
        float s = 0.f;
#pragma unroll
        for (int e = 0; e < 16; ++e) {
            float m = accum[e] * (1.0f / (float)M_TOK);
            s += m * logf(m * (float)E_ + 1e-9f);
        }
        out[pos] = s;
    }
}

// ---------------------------------------------------------------------------
extern "C" void kernel_launch(void* const* d_in, const int* in_sizes, int n_in,
                              void* d_out, int out_size, void* d_ws, size_t ws_size,
                              hipStream_t stream)
{
    const float* hidden = (const float*)d_in[0];
    const float* mimg   = (const float*)d_in[1];
    const float* mgen   = (const float*)d_in[2];
    const float* Wg1 = (const float*)d_in[3];
    const float* bg1 = (const float*)d_in[4];
    const float* Wg2 = (const float*)d_in[5];
    const float* bg2 = (const float*)d_in[6];
    const float* Wm1 = (const float*)d_in[7];
    const float* bm1 = (const float*)d_in[8];
    const float* Wm2 = (const float*)d_in[9];
    const float* bm2 = (const float*)d_in[10];
    const float* Ws1 = (const float*)d_in[11];  // [4,H,H2]
    const float* bs1 = (const float*)d_in[12];  // [4,H2]
    const float* Ws2 = (const float*)d_in[13];  // [4,H2,E]
    const float* bs2 = (const float*)d_in[14];  // [4,E]

    float* out = (float*)d_out;
    float* ws = (float*)d_ws;

    // workspace layout (floats)
    float* accum = ws;                                   // 16
    float* T1    = ws + 16;                              // [M,H]
    float* MISS  = T1   + (size_t)M_TOK * H_;            // [M,H]
    float* G1    = MISS + (size_t)M_TOK * H_;            // [M,H]
    float* S1    = G1   + (size_t)M_TOK * H_;            // [4][M,H2]
    float* GL    = S1   + (size_t)4 * M_TOK * H2_;       // [M,E]
    float* SL    = GL   + (size_t)M_TOK * E_;            // [4][M,E]

    hipMemsetAsync(d_out, 0, (size_t)out_size * sizeof(float), stream);
    hipMemsetAsync(accum, 0, 16 * sizeof(float), stream);

    const dim3 blk(256);

    // batch A: all GEMMs that depend only on inputs (768 active blocks, 3/CU)
    GPack pa;
    pa.g[0] = {hidden, Wm1, bm1, T1, H_, H_, 16, 1};
    pa.g[1] = {hidden, Wg1, bg1, G1, H_, H_, 16, 1};
    pa.g[2] = {mimg, Ws1 + (size_t)0 * H_ * H2_, bs1 + 0 * H2_,
               S1 + (size_t)0 * M_TOK * H2_, H_, H2_, 8, 1};
    pa.g[3] = {mgen, Ws1 + (size_t)1 * H_ * H2_, bs1 + 1 * H2_,
               S1 + (size_t)1 * M_TOK * H2_, H_, H2_, 8, 1};
    gemm128_kernel<<<dim3(16, M_TOK / 128, 4), blk, 0, stream>>>(pa);

    // MISS = T1 @ Wm2 + bm2
    GPack pb;
    pb.g[0] = {T1, Wm2, bm2, MISS, H_, H_, 16, 0};
    pb.g[1] = pb.g[0]; pb.g[2] = pb.g[0]; pb.g[3] = pb.g[0];
    gemm128_kernel<<<dim3(16, M_TOK / 128, 1), blk, 0, stream>>>(pb);

    // specialized routers on imputed modalities (clinical, biospecimen)
    GPack pc;
    pc.g[0] = {MISS, Ws1 + (size_t)2 * H_ * H2_, bs1 + 2 * H2_,
               S1 + (size_t)2 * M_TOK * H2_, H_, H2_, 8, 1};
    pc.g[1] = {MISS, Ws1 + (size_t)3 * H_ * H2_, bs1 + 3 * H2_,
               S1 + (size_t)3 * M_TOK * H2_, H_, H2_, 8, 1};
    pc.g[2] = pc.g[0]; pc.g[3] = pc.g[0];
    gemm128_kernel<<<dim3(8, M_TOK / 128, 2), blk, 0, stream>>>(pc);

    // all logit GEMMs
    SPack sp;
    sp.g[0] = {G1, Wg2, bg2, GL, H_};
    for (int m = 0; m < 4; ++m)
        sp.g[1 + m] = {S1 + (size_t)m * M_TOK * H2_, Ws2 + (size_t)m * H2_ * E_,
                       bs2 + (size_t)m * E_, SL + (size_t)m * M_TOK * E_, H2_};
    gemm_n16_kernel<<<dim3(M_TOK / 16, 1, 5), blk, 0, stream>>>(sp);

    router_kernel<<<M_TOK / 256, blk, 0, stream>>>(GL, SL, out, accum);
    aux_kernel<<<1, 64, 0, stream>>>(accum, out, (unsigned long long)out_size - 1);
}

// Round 3
// 1497.512 us; speedup vs baseline: 2.5469x; 2.5469x over previous
//
#include <hip/hip_runtime.h>
#include <math.h>

// Problem constants (B=4, S=512, H=2048, E=16, K=4)
#define M_TOK 2048   // B*S tokens
#define H_    2048
#define H2_   1024
#define E_    16
#define CAP_  768
#define ALPHA_ 0.7f

// ---------------------------------------------------------------------------
// Batched fp32 GEMM: C[M,N] = act(A[M,K] @ W[K,N] + bias[N])
// 128x128 tile, BK=16, 256 threads, 8x8 microtile. No prefetch regs (R2's
// spilled). Descriptor picked via uniform switch (dynamic kernarg indexing
// allocas to scratch). Swizzle: x = 4*mtile + nsub, y = ngroup -> XCD
// (flat%8) sees 8 m-panels x 4 n-panels (12MB; k-slices L2-resident).
// ---------------------------------------------------------------------------
struct GDesc {
    const float* A; const float* W; const float* bias; float* C;
    int K; int N; int ntn; int relu;   // ntn = N/128
};
struct GPack { GDesc g[4]; };

__global__ __launch_bounds__(256) void gemm128_kernel(GPack pack)
{
    GDesc d;
    switch (blockIdx.z) {               // uniform branch, no scratch alloca
        case 0: d = pack.g[0]; break;
        case 1: d = pack.g[1]; break;
        case 2: d = pack.g[2]; break;
        default: d = pack.g[3]; break;
    }
    const int mt = blockIdx.x >> 2;                 // m tile 0..15
    const int nt = (blockIdx.y << 2) + (blockIdx.x & 3);
    if (nt >= d.ntn) return;

    // pad 132: stores/reads <=2-way or broadcast; 528B keeps float4 align
    __shared__ float As[16][132];   // [k][m], transposed at store
    __shared__ float Bs[16][132];   // [k][n]

    const int tid = threadIdx.x;
    const int bm = mt * 128;
    const int bn = nt * 128;
    const int K = d.K, N = d.N;

    // A tile: 128 rows x 16 k; thread -> (row=tid>>2, k4=(tid&3)*4), rows +0/+64
    const int ar = tid >> 2;
    const int ak = (tid & 3) << 2;
    // B tile: 16 k x 128 n; thread -> (k=tid>>5, n4=(tid&31)*4), k +0/+8
    const int bk  = tid >> 5;
    const int bn4 = (tid & 31) << 2;

    const float* Aptr = d.A + (size_t)(bm + ar) * K + ak;
    const float* Wptr = d.W + (size_t)bk * N + bn + bn4;

    float acc[8][8];
#pragma unroll
    for (int i = 0; i < 8; ++i)
#pragma unroll
        for (int j = 0; j < 8; ++j) acc[i][j] = 0.f;

    const int tx = tid & 15;   // n group
    const int ty = tid >> 4;   // m group

    for (int k0 = 0; k0 < K; k0 += 16) {
        float4 a0 = *(const float4*)(Aptr + k0);
        float4 a1 = *(const float4*)(Aptr + k0 + (size_t)64 * K);
        float4 b0 = *(const float4*)(Wptr + (size_t)k0 * N);
        float4 b1 = *(const float4*)(Wptr + (size_t)(k0 + 8) * N);
        if (k0) __syncthreads();           // previous compute done before overwrite
        As[ak + 0][ar] = a0.x; As[ak + 1][ar] = a0.y;
        As[ak + 2][ar] = a0.z; As[ak + 3][ar] = a0.w;
        As[ak + 0][ar + 64] = a1.x; As[ak + 1][ar + 64] = a1.y;
        As[ak + 2][ar + 64] = a1.z; As[ak + 3][ar + 64] = a1.w;
        *(float4*)&Bs[bk][bn4]     = b0;
        *(float4*)&Bs[bk + 8][bn4] = b1;
        __syncthreads();

#pragma unroll
        for (int k = 0; k < 16; ++k) {
            float4 x0 = *(const float4*)&As[k][(ty << 3)];
            float4 x1 = *(const float4*)&As[k][(ty << 3) + 4];
            float4 y0 = *(const float4*)&Bs[k][(tx << 3)];
            float4 y1 = *(const float4*)&Bs[k][(tx << 3) + 4];
            float a[8] = {x0.x, x0.y, x0.z, x0.w, x1.x, x1.y, x1.z, x1.w};
            float b[8] = {y0.x, y0.y, y0.z, y0.w, y1.x, y1.y, y1.z, y1.w};
#pragma unroll
            for (int i = 0; i < 8; ++i)
#pragma unroll
                for (int j = 0; j < 8; ++j)
                    acc[i][j] = fmaf(a[i], b[j], acc[i][j]);
        }
    }

    const float4 bb0 = *(const float4*)&d.bias[bn + (tx << 3)];
    const float4 bb1 = *(const float4*)&d.bias[bn + (tx << 3) + 4];
    const float bv[8] = {bb0.x, bb0.y, bb0.z, bb0.w, bb1.x, bb1.y, bb1.z, bb1.w};
#pragma unroll
    for (int i = 0; i < 8; ++i) {
        const size_t row = (size_t)(bm + (ty << 3) + i);
        float o[8];
#pragma unroll
        for (int j = 0; j < 8; ++j) {
            o[j] = acc[i][j] + bv[j];
            if (d.relu) o[j] = fmaxf(o[j], 0.f);
        }
        float4 o0 = {o[0], o[1], o[2], o[3]};
        float4 o1 = {o[4], o[5], o[6], o[7]};
        *(float4*)&d.C[row * N + bn + (tx << 3)]     = o0;
        *(float4*)&d.C[row * N + bn + (tx << 3) + 4] = o1;
    }
}

// ---------------------------------------------------------------------------
// Batched skinny GEMM: C[M,16] = A[M,K] @ W[K,16] + bias[16]
// ---------------------------------------------------------------------------
struct SDesc { const float* A; const float* W; const float* bias; float* C; int K; };
struct SPack { SDesc g[5]; };

__global__ __launch_bounds__(256) void gemm_n16_kernel(SPack pack)
{
    SDesc d;
    switch (blockIdx.z) {
        case 0: d = pack.g[0]; break;
        case 1: d = pack.g[1]; break;
        case 2: d = pack.g[2]; break;
        case 3: d = pack.g[3]; break;
        default: d = pack.g[4]; break;
    }
    __shared__ float As[16][68];   // pad 68
    __shared__ float Ws[64][16];

    const int tid = threadIdx.x;
    const int e = tid & 15;
    const int r = tid >> 4;
    const int row0 = blockIdx.x * 16;

    const int lr  = tid >> 4;            // A load: row 0..15
    const int lk4 = (tid & 15) << 2;     // A load: k offset
    const int wk  = tid >> 2;            // W load: k row 0..63
    const int we4 = (tid & 3) << 2;      // W load: expert offset

    const int K = d.K;
    float acc = 0.f;
    for (int k0 = 0; k0 < K; k0 += 64) {
        float4 av = *(const float4*)&d.A[(size_t)(row0 + lr) * K + k0 + lk4];
        float4 wv = *(const float4*)&d.W[(size_t)(k0 + wk) * E_ + we4];
        if (k0) __syncthreads();
        *(float4*)&As[lr][lk4] = av;
        *(float4*)&Ws[wk][we4] = wv;
        __syncthreads();
#pragma unroll
        for (int kk = 0; kk < 64; kk += 4) {
            float4 a = *(const float4*)&As[r][kk];
            acc = fmaf(a.x, Ws[kk + 0][e], acc);
            acc = fmaf(a.y, Ws[kk + 1][e], acc);
            acc = fmaf(a.z, Ws[kk + 2][e], acc);
            acc = fmaf(a.w, Ws[kk + 3][e], acc);
        }
    }
    d.C[(size_t)(row0 + r) * E_ + e] = acc + d.bias[e];
}

// ---------------------------------------------------------------------------
// Router finalize
// ---------------------------------------------------------------------------
__device__ __forceinline__ void softmax16_acc(const float* __restrict__ lg,
                                              float w, float* __restrict__ p)
{
    float mx = lg[0];
#pragma unroll
    for (int e = 1; e < 16; ++e) mx = fmaxf(mx, lg[e]);
    float ex[16];
    float s = 0.f;
#pragma unroll
    for (int e = 0; e < 16; ++e) { ex[e] = expf(lg[e] - mx); s += ex[e]; }
    const float wi = w / s;
#pragma unroll
    for (int e = 0; e < 16; ++e) p[e] = fmaf(ex[e], wi, p[e]);
}

__global__ __launch_bounds__(256) void router_kernel(
    const float* __restrict__ GL,   // [M,16]
    const float* __restrict__ SL,   // [4,M,16]
    float* __restrict__ out, float* __restrict__ accum)
{
    const int t = blockIdx.x * 256 + threadIdx.x;

    float p[16];
#pragma unroll
    for (int e = 0; e < 16; ++e) p[e] = 0.f;

    softmax16_acc(GL + (size_t)t * E_, ALPHA_, p);
#pragma unroll
    for (int m = 0; m < 4; ++m)
        softmax16_acc(SL + ((size_t)m * M_TOK + t) * E_, (1.f - ALPHA_) * 0.5f, p);

    const size_t NTOT = (size_t)M_TOK * E_ * CAP_;
    float* probs_out = out + 2 * NTOT + (size_t)t * E_;
#pragma unroll
    for (int e = 0; e < 16; ++e) probs_out[e] = p[e];

    // wave butterfly -> one atomic per expert per wave
    float red[16];
#pragma unroll
    for (int e = 0; e < 16; ++e) red[e] = p[e];
#pragma unroll
    for (int m = 1; m < 64; m <<= 1)
#pragma unroll
        for (int e = 0; e < 16; ++e) red[e] += __shfl_xor(red[e], m);
    const int lane = threadIdx.x & 63;
#pragma unroll
    for (int e = 0; e < 16; ++e)
        if (lane == e) atomicAdd(&accum[e], red[e]);

    // top-4, ties -> lowest index (matches jax.lax.top_k)
    float tmp[16];
#pragma unroll
    for (int e = 0; e < 16; ++e) tmp[e] = p[e];
    int   bi[4];
    float bv[4];
    float s4 = 0.f;
#pragma unroll
    for (int kk = 0; kk < 4; ++kk) {
        float best = -1.f; int besti = 0;
#pragma unroll
        for (int e = 0; e < 16; ++e)
            if (tmp[e] > best) { best = tmp[e]; besti = e; }
        bi[kk] = besti; bv[kk] = best; s4 += best;
        tmp[besti] = -1.f;
    }
    const float inv = 1.f / s4;
#pragma unroll
    for (int kk = 0; kk < 4; ++kk) {
        const size_t base = ((size_t)t * E_ + bi[kk]) * CAP_;
        out[base] = 1.0f;                    // dispatch_tensor slot 0
        out[NTOT + base] = bv[kk] * inv;     // combine_tensor  slot 0
    }
}

__global__ void aux_kernel(const float* __restrict__ accum,
                           float* __restrict__ out, unsigned long long pos)
{
    if (threadIdx.x == 0 && blockIdx.x == 0) {
        float s = 0.f;
#pragma unroll
        for (int e = 0; e < 16; ++e) {
            float m = accum[e] * (1.0f / (float)M_TOK);
            s += m * logf(m * (float)E_ + 1e-9f);
        }
        out[pos] = s;
    }
}

// ---------------------------------------------------------------------------
extern "C" void kernel_launch(void* const* d_in, const int* in_sizes, int n_in,
                              void* d_out, int out_size, void* d_ws, size_t ws_size,
                              hipStream_t stream)
{
    const float* hidden = (const float*)d_in[0];
    const float* mimg   = (const float*)d_in[1];
    const float* mgen   = (const float*)d_in[2];
    const float* Wg1 = (const float*)d_in[3];
    const float* bg1 = (const float*)d_in[4];
    const float* Wg2 = (const float*)d_in[5];
    const float* bg2 = (const float*)d_in[6];
    const float* Wm1 = (const float*)d_in[7];
    const float* bm1 = (const float*)d_in[8];
    const float* Wm2 = (const float*)d_in[9];
    const float* bm2 = (const float*)d_in[10];
    const float* Ws1 = (const float*)d_in[11];  // [4,H,H2]
    const float* bs1 = (const float*)d_in[12];  // [4,H2]
    const float* Ws2 = (const float*)d_in[13];  // [4,H2,E]
    const float* bs2 = (const float*)d_in[14];  // [4,E]

    float* out = (float*)d_out;
    float* ws = (float*)d_ws;

    // workspace layout (floats)
    float* accum = ws;                                   // 16
    float* T1    = ws + 16;                              // [M,H]
    float* MISS  = T1   + (size_t)M_TOK * H_;            // [M,H]
    float* G1    = MISS + (size_t)M_TOK * H_;            // [M,H]
    float* S1    = G1   + (size_t)M_TOK * H_;            // [4][M,H2]
    float* GL    = S1   + (size_t)4 * M_TOK * H2_;       // [M,E]
    float* SL    = GL   + (size_t)M_TOK * E_;            // [4][M,E]

    hipMemsetAsync(d_out, 0, (size_t)out_size * sizeof(float), stream);
    hipMemsetAsync(accum, 0, 16 * sizeof(float), stream);

    const dim3 blk(256);

    // batch A: GEMMs depending only on inputs (768 active blocks)
    GPack pa;
    pa.g[0] = {hidden, Wm1, bm1, T1, H_, H_, 16, 1};
    pa.g[1] = {hidden, Wg1, bg1, G1, H_, H_, 16, 1};
    pa.g[2] = {mimg, Ws1 + (size_t)0 * H_ * H2_, bs1 + 0 * H2_,
               S1 + (size_t)0 * M_TOK * H2_, H_, H2_, 8, 1};
    pa.g[3] = {mgen, Ws1 + (size_t)1 * H_ * H2_, bs1 + 1 * H2_,
               S1 + (size_t)1 * M_TOK * H2_, H_, H2_, 8, 1};
    gemm128_kernel<<<dim3(64, 4, 4), blk, 0, stream>>>(pa);

    // MISS = T1 @ Wm2 + bm2
    GPack pb;
    pb.g[0] = {T1, Wm2, bm2, MISS, H_, H_, 16, 0};
    pb.g[1] = pb.g[0]; pb.g[2] = pb.g[0]; pb.g[3] = pb.g[0];
    gemm128_kernel<<<dim3(64, 4, 1), blk, 0, stream>>>(pb);

    // specialized routers on imputed modalities (clinical, biospecimen)
    GPack pc;
    pc.g[0] = {MISS, Ws1 + (size_t)2 * H_ * H2_, bs1 + 2 * H2_,
               S1 + (size_t)2 * M_TOK * H2_, H_, H2_, 8, 1};
    pc.g[1] = {MISS, Ws1 + (size_t)3 * H_ * H2_, bs1 + 3 * H2_,
               S1 + (size_t)3 * M_TOK * H2_, H_, H2_, 8, 1};
    pc.g[2] = pc.g[0]; pc.g[3] = pc.g[0];
    gemm128_kernel<<<dim3(64, 2, 2), blk, 0, stream>>>(pc);

    // all logit GEMMs
    SPack sp;
    sp.g[0] = {G1, Wg2, bg2, GL, H_};
    for (int m = 0; m < 4; ++m)
        sp.g[1 + m] = {S1 + (size_t)m * M_TOK * H2_, Ws2 + (size_t)m * H2_ * E_,
                       bs2 + (size_t)m * E_, SL + (size_t)m * M_TOK * E_, H2_};
    gemm_n16_kernel<<<dim3(M_TOK / 16, 1, 5), blk, 0, stream>>>(sp);

    router_kernel<<<M_TOK / 256, blk, 0, stream>>>(GL, SL, out, accum);
    aux_kernel<<<1, 64, 0, stream>>>(accum, out, (unsigned long long)out_size - 1);
}

// Round 4
// 718.267 us; speedup vs baseline: 5.3100x; 2.0849x over previous
//
#include <hip/hip_runtime.h>
#include <math.h>

// Problem constants (B=4, S=512, H=2048, E=16, K=4)
#define M_TOK 2048
#define H_    2048
#define H2_   1024
#define E_    16
#define CAP_  768
#define ALPHA_ 0.7f
#define WSCALE 64.0f
#define INV_WSCALE (1.0f / 64.0f)

typedef _Float16 half8 __attribute__((ext_vector_type(8)));
typedef float f32x4 __attribute__((ext_vector_type(4)));

typedef __attribute__((address_space(1))) const unsigned int* gas_ptr;
typedef __attribute__((address_space(3))) unsigned int* las_ptr;

__device__ __forceinline__ void load_lds16(const void* g, void* l) {
    __builtin_amdgcn_global_load_lds((gas_ptr)g, (las_ptr)l, 16, 0, 0);
}

// split 8 fp32 -> half8 hi + half8 lo
__device__ __forceinline__ void split8(const f32x4 a, const f32x4 b,
                                       half8* hi, half8* lo) {
#pragma unroll
    for (int i = 0; i < 4; ++i) {
        _Float16 h0 = (_Float16)a[i];
        (*hi)[i] = h0;
        (*lo)[i] = (_Float16)(a[i] - (float)h0);
        _Float16 h1 = (_Float16)b[i];
        (*hi)[i + 4] = h1;
        (*lo)[i + 4] = (_Float16)(b[i] - (float)h1);
    }
}

// ---------------------------------------------------------------------------
// Weight split+transpose: W fp32 [K,N] -> Wt_h/Wt_l f16 [N,K], scaled by 64.
// 64x64 tile through LDS.
// ---------------------------------------------------------------------------
struct WDesc { const float* W; _Float16* oh; _Float16* ol; int K; int N; };
struct WPack { WDesc g[7]; };

__global__ __launch_bounds__(256) void wsplit_kernel(WPack pack)
{
    WDesc d;
    switch (blockIdx.z) {
        case 0: d = pack.g[0]; break;
        case 1: d = pack.g[1]; break;
        case 2: d = pack.g[2]; break;
        case 3: d = pack.g[3]; break;
        case 4: d = pack.g[4]; break;
        case 5: d = pack.g[5]; break;
        default: d = pack.g[6]; break;
    }
    const int n0 = blockIdx.y * 64;
    if (n0 >= d.N) return;
    const int k0 = blockIdx.x * 64;

    __shared__ float T[64][68];   // [n][k], transposed at store
    const int t = threadIdx.x;

    {   // load 64k x 64n tile by k-rows (coalesced), store transposed
        const int kr = t >> 2;               // 0..63
        const int c0 = (t & 3) << 4;         // 0,16,32,48
        const float* src = d.W + (size_t)(k0 + kr) * d.N + n0 + c0;
        f32x4 v0 = *(const f32x4*)(src);
        f32x4 v1 = *(const f32x4*)(src + 4);
        f32x4 v2 = *(const f32x4*)(src + 8);
        f32x4 v3 = *(const f32x4*)(src + 12);
#pragma unroll
        for (int i = 0; i < 4; ++i) T[c0 + i][kr]      = v0[i];
#pragma unroll
        for (int i = 0; i < 4; ++i) T[c0 + 4 + i][kr]  = v1[i];
#pragma unroll
        for (int i = 0; i < 4; ++i) T[c0 + 8 + i][kr]  = v2[i];
#pragma unroll
        for (int i = 0; i < 4; ++i) T[c0 + 12 + i][kr] = v3[i];
    }
    __syncthreads();

    {   // write out [n][k] as f16 hi/lo, scaled by 64
        const int n  = t >> 2;               // 0..63
        const int kj = (t & 3) << 4;         // 0,16,32,48
        half8 h0, l0, h1, l1;
        f32x4 u0 = *(const f32x4*)&T[n][kj];
        f32x4 u1 = *(const f32x4*)&T[n][kj + 4];
        f32x4 u2 = *(const f32x4*)&T[n][kj + 8];
        f32x4 u3 = *(const f32x4*)&T[n][kj + 12];
        u0 *= WSCALE; u1 *= WSCALE; u2 *= WSCALE; u3 *= WSCALE;
        split8(u0, u1, &h0, &l0);
        split8(u2, u3, &h1, &l1);
        const size_t o = (size_t)(n0 + n) * d.K + k0 + kj;
        *(half8*)(d.oh + o)     = h0;
        *(half8*)(d.oh + o + 8) = h1;
        *(half8*)(d.ol + o)     = l0;
        *(half8*)(d.ol + o + 8) = l1;
    }
}

// ---------------------------------------------------------------------------
// f16x3 MFMA GEMM: C[M,N] = act((A @ (W*64))/64 + bias)
// A fp32 [M,K] split on the fly; W pre-split/transposed f16 [N,K].
// 128x128 tile, BK=32, 4 waves x (64x64), 16x16x32 MFMA, swizzled LDS.
// ---------------------------------------------------------------------------
struct GDesc {
    const float* A; const _Float16* Wh; const _Float16* Wl;
    const float* bias; float* C; int K; int N; int ntn; int relu;
};
struct GPack { GDesc g[4]; };

__global__ __launch_bounds__(256) void gemm_mfma_kernel(GPack pack)
{
    GDesc d;
    switch (blockIdx.z) {
        case 0: d = pack.g[0]; break;
        case 1: d = pack.g[1]; break;
        case 2: d = pack.g[2]; break;
        default: d = pack.g[3]; break;
    }
    const int mt_ = blockIdx.x >> 2;
    const int nt_ = (blockIdx.y << 2) + (blockIdx.x & 3);
    if (nt_ >= d.ntn) return;
    const int bm = mt_ * 128, bn = nt_ * 128;
    const int K = d.K, N = d.N;

    // [row][4 granules of 8 halves], granule slot = r*4 + ((q + (r>>1))&3)
    __shared__ _Float16 Ah_s[128 * 32];
    __shared__ _Float16 Al_s[128 * 32];
    __shared__ _Float16 Bh_s[128 * 32];
    __shared__ _Float16 Bl_s[128 * 32];

    const int tid  = threadIdx.x;
    const int lane = tid & 63;
    const int wave = tid >> 6;
    const int wm = wave >> 1, wn = wave & 1;

    // A staging: row ar = tid>>1, 16 consecutive k at kc
    const int ar  = tid >> 1;
    const int akc = (tid & 1) << 4;
    const int aq0 = (tid & 1) << 1;                       // chunk index base
    const int ag0 = ar * 4 + ((aq0 + 0 + (ar >> 1)) & 3); // LDS granule slots
    const int ag1 = ar * 4 + ((aq0 + 1 + (ar >> 1)) & 3);
    const float* Aptr = d.A + (size_t)(bm + ar) * K + akc;

    // B staging via global_load_lds: slot g holds chunk (n=g>>2, q=((g&3)-(n>>1))&3)
    int bn_g[2], bq_g[2];
#pragma unroll
    for (int is = 0; is < 2; ++is) {
        const int g = tid + (is << 8);
        const int n = g >> 2;
        bn_g[is] = n;
        bq_g[is] = ((g & 3) - (n >> 1)) & 3;
    }

    // fragment read granules (swizzle: s = (q + (row>>1))&3, q = lane>>4;
    // row = base + mt*16 keeps s invariant since 8*mt % 4 == 0)
    const int am0  = wm * 64 + (lane & 15);
    const int aoff = (am0 * 4 + (((lane >> 4) + (am0 >> 1)) & 3)) * 8;
    const int bn0  = wn * 64 + (lane & 15);
    const int boff = (bn0 * 4 + (((lane >> 4) + (bn0 >> 1)) & 3)) * 8;

    f32x4 acc[4][4];
#pragma unroll
    for (int i = 0; i < 4; ++i)
#pragma unroll
        for (int j = 0; j < 4; ++j) acc[i][j] = (f32x4)0.f;

    for (int k0 = 0; k0 < K; k0 += 32) {
        f32x4 v0 = *(const f32x4*)(Aptr + k0);
        f32x4 v1 = *(const f32x4*)(Aptr + k0 + 4);
        f32x4 v2 = *(const f32x4*)(Aptr + k0 + 8);
        f32x4 v3 = *(const f32x4*)(Aptr + k0 + 12);

        if (k0) __syncthreads();   // prev tile fully consumed before overwrite

        // B: DMA straight to LDS (after barrier!)
#pragma unroll
        for (int is = 0; is < 2; ++is) {
            const size_t go = (size_t)(bn + bn_g[is]) * K + k0 + bq_g[is] * 8;
            load_lds16(d.Wh + go, &Bh_s[(size_t)(tid + (is << 8)) * 8]);
            load_lds16(d.Wl + go, &Bl_s[(size_t)(tid + (is << 8)) * 8]);
        }

        // A: split in registers, swizzled LDS store
        half8 h0, l0, h1, l1;
        split8(v0, v1, &h0, &l0);
        split8(v2, v3, &h1, &l1);
        *(half8*)&Ah_s[ag0 * 8] = h0;
        *(half8*)&Al_s[ag0 * 8] = l0;
        *(half8*)&Ah_s[ag1 * 8] = h1;
        *(half8*)&Al_s[ag1 * 8] = l1;

        __syncthreads();   // drains DMA (vmcnt) + ds_write (lgkm)

        half8 fAh[4], fAl[4];
#pragma unroll
        for (int mt = 0; mt < 4; ++mt) {
            fAh[mt] = *(const half8*)&Ah_s[aoff + mt * 512];
            fAl[mt] = *(const half8*)&Al_s[aoff + mt * 512];
        }
#pragma unroll
        for (int nt = 0; nt < 4; ++nt) {
            half8 fBh = *(const half8*)&Bh_s[boff + nt * 512];
            half8 fBl = *(const half8*)&Bl_s[boff + nt * 512];
#pragma unroll
            for (int mt = 0; mt < 4; ++mt) {
                acc[mt][nt] = __builtin_amdgcn_mfma_f32_16x16x32_f16(
                    fAh[mt], fBh, acc[mt][nt], 0, 0, 0);
                acc[mt][nt] = __builtin_amdgcn_mfma_f32_16x16x32_f16(
                    fAh[mt], fBl, acc[mt][nt], 0, 0, 0);
                acc[mt][nt] = __builtin_amdgcn_mfma_f32_16x16x32_f16(
                    fAl[mt], fBh, acc[mt][nt], 0, 0, 0);
            }
        }
    }

    // epilogue: C/D layout col=lane&15, row=(lane>>4)*4+reg
    const int erow0 = bm + wm * 64 + ((lane >> 4) << 2);
    const int ecol0 = bn + wn * 64 + (lane & 15);
#pragma unroll
    for (int nt = 0; nt < 4; ++nt) {
        const int col = ecol0 + nt * 16;
        const float bb = d.bias[col];
#pragma unroll
        for (int mt = 0; mt < 4; ++mt) {
            f32x4 a = acc[mt][nt];
#pragma unroll
            for (int r = 0; r < 4; ++r) {
                float v = a[r] * INV_WSCALE + bb;
                if (d.relu) v = fmaxf(v, 0.f);
                d.C[(size_t)(erow0 + mt * 16 + r) * N + col] = v;
            }
        }
    }
}

// ---------------------------------------------------------------------------
// Batched skinny GEMM: C[M,16] = A[M,K] @ W[K,16] + bias[16]   (fp32, as R3)
// ---------------------------------------------------------------------------
struct SDesc { const float* A; const float* W; const float* bias; float* C; int K; };
struct SPack { SDesc g[5]; };

__global__ __launch_bounds__(256) void gemm_n16_kernel(SPack pack)
{
    SDesc d;
    switch (blockIdx.z) {
        case 0: d = pack.g[0]; break;
        case 1: d = pack.g[1]; break;
        case 2: d = pack.g[2]; break;
        case 3: d = pack.g[3]; break;
        default: d = pack.g[4]; break;
    }
    __shared__ float As[16][68];
    __shared__ float Ws[64][16];

    const int tid = threadIdx.x;
    const int e = tid & 15;
    const int r = tid >> 4;
    const int row0 = blockIdx.x * 16;

    const int lr  = tid >> 4;
    const int lk4 = (tid & 15) << 2;
    const int wk  = tid >> 2;
    const int we4 = (tid & 3) << 2;

    const int K = d.K;
    float acc = 0.f;
    for (int k0 = 0; k0 < K; k0 += 64) {
        float4 av = *(const float4*)&d.A[(size_t)(row0 + lr) * K + k0 + lk4];
        float4 wv = *(const float4*)&d.W[(size_t)(k0 + wk) * E_ + we4];
        if (k0) __syncthreads();
        *(float4*)&As[lr][lk4] = av;
        *(float4*)&Ws[wk][we4] = wv;
        __syncthreads();
#pragma unroll
        for (int kk = 0; kk < 64; kk += 4) {
            float4 a = *(const float4*)&As[r][kk];
            acc = fmaf(a.x, Ws[kk + 0][e], acc);
            acc = fmaf(a.y, Ws[kk + 1][e], acc);
            acc = fmaf(a.z, Ws[kk + 2][e], acc);
            acc = fmaf(a.w, Ws[kk + 3][e], acc);
        }
    }
    d.C[(size_t)(row0 + r) * E_ + e] = acc + d.bias[e];
}

// ---------------------------------------------------------------------------
// Router finalize (as R3)
// ---------------------------------------------------------------------------
__device__ __forceinline__ void softmax16_acc(const float* __restrict__ lg,
                                              float w, float* __restrict__ p)
{
    float mx = lg[0];
#pragma unroll
    for (int e = 1; e < 16; ++e) mx = fmaxf(mx, lg[e]);
    float ex[16];
    float s = 0.f;
#pragma unroll
    for (int e = 0; e < 16; ++e) { ex[e] = expf(lg[e] - mx); s += ex[e]; }
    const float wi = w / s;
#pragma unroll
    for (int e = 0; e < 16; ++e) p[e] = fmaf(ex[e], wi, p[e]);
}

__global__ __launch_bounds__(256) void router_kernel(
    const float* __restrict__ GL, const float* __restrict__ SL,
    float* __restrict__ out, float* __restrict__ accum)
{
    const int t = blockIdx.x * 256 + threadIdx.x;

    float p[16];
#pragma unroll
    for (int e = 0; e < 16; ++e) p[e] = 0.f;

    softmax16_acc(GL + (size_t)t * E_, ALPHA_, p);
#pragma unroll
    for (int m = 0; m < 4; ++m)
        softmax16_acc(SL + ((size_t)m * M_TOK + t) * E_, (1.f - ALPHA_) * 0.5f, p);

    const size_t NTOT = (size_t)M_TOK * E_ * CAP_;
    float* probs_out = out + 2 * NTOT + (size_t)t * E_;
#pragma unroll
    for (int e = 0; e < 16; ++e) probs_out[e] = p[e];

    float red[16];
#pragma unroll
    for (int e = 0; e < 16; ++e) red[e] = p[e];
#pragma unroll
    for (int m = 1; m < 64; m <<= 1)
#pragma unroll
        for (int e = 0; e < 16; ++e) red[e] += __shfl_xor(red[e], m);
    const int lane = threadIdx.x & 63;
#pragma unroll
    for (int e = 0; e < 16; ++e)
        if (lane == e) atomicAdd(&accum[e], red[e]);

    float tmp[16];
#pragma unroll
    for (int e = 0; e < 16; ++e) tmp[e] = p[e];
    int   bi[4];
    float bv[4];
    float s4 = 0.f;
#pragma unroll
    for (int kk = 0; kk < 4; ++kk) {
        float best = -1.f; int besti = 0;
#pragma unroll
        for (int e = 0; e < 16; ++e)
            if (tmp[e] > best) { best = tmp[e]; besti = e; }
        bi[kk] = besti; bv[kk] = best; s4 += best;
        tmp[besti] = -1.f;
    }
    const float inv = 1.f / s4;
#pragma unroll
    for (int kk = 0; kk < 4; ++kk) {
        const size_t base = ((size_t)t * E_ + bi[kk]) * CAP_;
        out[base] = 1.0f;
        out[NTOT + base] = bv[kk] * inv;
    }
}

__global__ void aux_kernel(const float* __restrict__ accum,
                           float* __restrict__ out, unsigned long long pos)
{
    if (threadIdx.x == 0 && blockIdx.x == 0) {
        float s = 0.f;
#pragma unroll
        for (int e = 0; e < 16; ++e) {
            float m = accum[e] * (1.0f / (float)M_TOK);
            s += m * logf(m * (float)E_ + 1e-9f);
        }
        out[pos] = s;
    }
}

// ---------------------------------------------------------------------------
extern "C" void kernel_launch(void* const* d_in, const int* in_sizes, int n_in,
                              void* d_out, int out_size, void* d_ws, size_t ws_size,
                              hipStream_t stream)
{
    const float* hidden = (const float*)d_in[0];
    const float* mimg   = (const float*)d_in[1];
    const float* mgen   = (const float*)d_in[2];
    const float* Wg1 = (const float*)d_in[3];
    const float* bg1 = (const float*)d_in[4];
    const float* Wg2 = (const float*)d_in[5];
    const float* bg2 = (const float*)d_in[6];
    const float* Wm1 = (const float*)d_in[7];
    const float* bm1 = (const float*)d_in[8];
    const float* Wm2 = (const float*)d_in[9];
    const float* bm2 = (const float*)d_in[10];
    const float* Ws1 = (const float*)d_in[11];  // [4,H,H2]
    const float* bs1 = (const float*)d_in[12];  // [4,H2]
    const float* Ws2 = (const float*)d_in[13];  // [4,H2,E]
    const float* bs2 = (const float*)d_in[14];  // [4,E]

    float* out = (float*)d_out;

    // workspace layout
    char* p = (char*)d_ws;
    float* accum = (float*)p;               p += 256;
    float* T1    = (float*)p;               p += (size_t)M_TOK * H_ * 4;
    float* MISS  = (float*)p;               p += (size_t)M_TOK * H_ * 4;
    float* G1    = (float*)p;               p += (size_t)M_TOK * H_ * 4;
    float* S1    = (float*)p;               p += (size_t)4 * M_TOK * H2_ * 4;
    float* GL    = (float*)p;               p += (size_t)M_TOK * E_ * 4;
    float* SL    = (float*)p;               p += (size_t)4 * M_TOK * E_ * 4;
    _Float16* Wm1t_h = (_Float16*)p;        p += (size_t)H_ * H_ * 2;
    _Float16* Wm1t_l = (_Float16*)p;        p += (size_t)H_ * H_ * 2;
    _Float16* Wg1t_h = (_Float16*)p;        p += (size_t)H_ * H_ * 2;
    _Float16* Wg1t_l = (_Float16*)p;        p += (size_t)H_ * H_ * 2;
    _Float16* Wm2t_h = (_Float16*)p;        p += (size_t)H_ * H_ * 2;
    _Float16* Wm2t_l = (_Float16*)p;        p += (size_t)H_ * H_ * 2;
    _Float16* Ws1t_h = (_Float16*)p;        p += (size_t)4 * H2_ * H_ * 2;
    _Float16* Ws1t_l = (_Float16*)p;        p += (size_t)4 * H2_ * H_ * 2;

    hipMemsetAsync(d_out, 0, (size_t)out_size * sizeof(float), stream);
    hipMemsetAsync(accum, 0, 16 * sizeof(float), stream);

    const dim3 blk(256);

    // 1) weight split+transpose (scaled by 64)
    WPack wp;
    wp.g[0] = {Wm1, Wm1t_h, Wm1t_l, H_, H_};
    wp.g[1] = {Wg1, Wg1t_h, Wg1t_l, H_, H_};
    wp.g[2] = {Wm2, Wm2t_h, Wm2t_l, H_, H_};
    for (int m = 0; m < 4; ++m)
        wp.g[3 + m] = {Ws1 + (size_t)m * H_ * H2_,
                       Ws1t_h + (size_t)m * H2_ * H_,
                       Ws1t_l + (size_t)m * H2_ * H_, H_, H2_};
    wsplit_kernel<<<dim3(32, 32, 7), blk, 0, stream>>>(wp);

    // 2) batch A: input-only GEMMs
    GPack pa;
    pa.g[0] = {hidden, Wm1t_h, Wm1t_l, bm1, T1, H_, H_, 16, 1};
    pa.g[1] = {hidden, Wg1t_h, Wg1t_l, bg1, G1, H_, H_, 16, 1};
    pa.g[2] = {mimg, Ws1t_h + (size_t)0 * H2_ * H_, Ws1t_l + (size_t)0 * H2_ * H_,
               bs1 + 0 * H2_, S1 + (size_t)0 * M_TOK * H2_, H_, H2_, 8, 1};
    pa.g[3] = {mgen, Ws1t_h + (size_t)1 * H2_ * H_, Ws1t_l + (size_t)1 * H2_ * H_,
               bs1 + 1 * H2_, S1 + (size_t)1 * M_TOK * H2_, H_, H2_, 8, 1};
    gemm_mfma_kernel<<<dim3(64, 4, 4), blk, 0, stream>>>(pa);

    // 3) MISS = T1 @ Wm2 + bm2 (no relu)
    GPack pb;
    pb.g[0] = {T1, Wm2t_h, Wm2t_l, bm2, MISS, H_, H_, 16, 0};
    pb.g[1] = pb.g[0]; pb.g[2] = pb.g[0]; pb.g[3] = pb.g[0];
    gemm_mfma_kernel<<<dim3(64, 4, 1), blk, 0, stream>>>(pb);

    // 4) specialized routers on imputed modalities
    GPack pc;
    pc.g[0] = {MISS, Ws1t_h + (size_t)2 * H2_ * H_, Ws1t_l + (size_t)2 * H2_ * H_,
               bs1 + 2 * H2_, S1 + (size_t)2 * M_TOK * H2_, H_, H2_, 8, 1};
    pc.g[1] = {MISS, Ws1t_h + (size_t)3 * H2_ * H_, Ws1t_l + (size_t)3 * H2_ * H_,
               bs1 + 3 * H2_, S1 + (size_t)3 * M_TOK * H2_, H_, H2_, 8, 1};
    pc.g[2] = pc.g[0]; pc.g[3] = pc.g[0];
    gemm_mfma_kernel<<<dim3(64, 2, 2), blk, 0, stream>>>(pc);

    // 5) logit GEMMs (fp32)
    SPack sp;
    sp.g[0] = {G1, Wg2, bg2, GL, H_};
    for (int m = 0; m < 4; ++m)
        sp.g[1 + m] = {S1 + (size_t)m * M_TOK * H2_, Ws2 + (size_t)m * H2_ * E_,
                       bs2 + (size_t)m * E_, SL + (size_t)m * M_TOK * E_, H2_};
    gemm_n16_kernel<<<dim3(M_TOK / 16, 1, 5), blk, 0, stream>>>(sp);

    // 6) finalize
    router_kernel<<<M_TOK / 256, blk, 0, stream>>>(GL, SL, out, accum);
    aux_kernel<<<1, 64, 0, stream>>>(accum, out, (unsigned long long)out_size - 1);
}